// Round 4
// baseline (478.510 us; speedup 1.0000x reference)
//
#include <hip/hip_runtime.h>

// Problem constants
#define DM   1024
#define MR   8192          // L*B rows
#define LKK  1025
#define OUTOFF 8388608     // MR*DM floats, start of attn region in d_out
#define VPADF 24           // front pad rows of vbuf (covers shift -3..-1)

typedef short bf16x8 __attribute__((ext_vector_type(8)));
typedef float f32x4  __attribute__((ext_vector_type(4)));
typedef unsigned short u16;
typedef u16 u16x8 __attribute__((ext_vector_type(8)));

__device__ __forceinline__ u16 f2bf(float f) {
  union { float f; unsigned u; } v; v.f = f;
  return (u16)((v.u + 0x7fffu + ((v.u >> 16) & 1u)) >> 16);  // RNE
}

__device__ __forceinline__ void gl_lds16(const u16* g, u16* l) {
  __builtin_amdgcn_global_load_lds((const __attribute__((address_space(1))) void*)g,
                                   (__attribute__((address_space(3))) void*)l,
                                   16, 0, 0);
}

// BK=64 staging: lane i of wave w, round r loads global row r*32+w*8+(i&7),
// k-chunk (i>>3)*8 (16 B). LDS dest = wave-uniform base + lane*16B (HW rule),
// giving layout [rowgrp8 g][kq 0..7][rowin 0..7][8 u16], 512 u16 per group.
// Frag reads then have 16B lane stride -> banks fully spread (2-way max, free).
#define STAGE64(gbase, lds)                                                    \
  _Pragma("unroll")                                                            \
  for (int r = 0; r < 4; r++)                                                  \
    gl_lds16((gbase) + (size_t)(r * 32 + wave * 8 + rowin) * DM + kc,          \
             (lds) + (r * 4 + wave) * 512 + ldso);

// One BK=64 MFMA block: each wave computes 64x64 via 2x(4x4) frags of 16x16x32
#define MFMA64(As, Bs)                                                         \
  _Pragma("unroll")                                                            \
  for (int kb = 0; kb < 2; kb++) {                                             \
    bf16x8 af[4], bg[4];                                                       \
    int kq = kb * 4 + kq0;                                                     \
    _Pragma("unroll")                                                          \
    for (int i = 0; i < 4; i++) {                                              \
      int row = wm + i * 16 + lr;                                              \
      af[i] = *(const bf16x8*)((As) + (row >> 3) * 512 + kq * 64 + (row & 7) * 8); \
    }                                                                          \
    _Pragma("unroll")                                                          \
    for (int j = 0; j < 4; j++) {                                              \
      int row = wn + j * 16 + lr;                                              \
      bg[j] = *(const bf16x8*)((Bs) + (row >> 3) * 512 + kq * 64 + (row & 7) * 8); \
    }                                                                          \
    _Pragma("unroll")                                                          \
    for (int i = 0; i < 4; i++)                                                \
      _Pragma("unroll")                                                        \
      for (int j = 0; j < 4; j++)                                              \
        acc[i][j] = __builtin_amdgcn_mfma_f32_16x16x32_bf16(af[i], bg[j], acc[i][j], 0, 0, 0); \
  }

// XCD-friendly tile mapping for 512 blocks (64 m-tiles x 8 n-tiles):
// XCD = blockIdx % 8 sees only 8 m-tiles -> A slice 2MB + B 2MB fit per-XCD L2.
__device__ __forceinline__ void tile_of(int b, int& m0, int& n0) {
  int mt = (b & 7) * 8 + ((b >> 3) & 7);
  int nt = b >> 6;
  m0 = mt * 128; n0 = nt * 128;
}

// Convert value/Wv/Wo f32->bf16 and zero vbuf pad rows. 8 elems/thread.
__global__ __launch_bounds__(256) void convert_k(const float* __restrict__ value,
                                                 const float* __restrict__ Wv,
                                                 const float* __restrict__ Wo,
                                                 u16* __restrict__ valb,
                                                 u16* __restrict__ Wvb,
                                                 u16* __restrict__ Wob,
                                                 u16* __restrict__ vbuf) {
  size_t c = (size_t)blockIdx.x * 256 + threadIdx.x;
  const size_t C1 = 1048576;            // value: 8388608/8
  const size_t C2 = C1 + 131072;        // + Wv
  const size_t C3 = C2 + 131072;        // + Wo = 1310720
  const size_t C4 = C3 + 7168;          // + pad rows (24+32 rows)
  if (c < C3) {
    const float* s; u16* d; size_t off;
    if (c < C1)      { s = value; d = valb; off = c * 8; }
    else if (c < C2) { s = Wv;    d = Wvb;  off = (c - C1) * 8; }
    else             { s = Wo;    d = Wob;  off = (c - C2) * 8; }
    float4 a = *(const float4*)(s + off);
    float4 b = *(const float4*)(s + off + 4);
    u16x8 p;
    p[0]=f2bf(a.x); p[1]=f2bf(a.y); p[2]=f2bf(a.z); p[3]=f2bf(a.w);
    p[4]=f2bf(b.x); p[5]=f2bf(b.y); p[6]=f2bf(b.z); p[7]=f2bf(b.w);
    *(u16x8*)(d + off) = p;
  } else if (c < C4) {
    size_t j = c - C3;
    u16x8 z = {0,0,0,0,0,0,0,0};
    if (j < 3072) *(u16x8*)(vbuf + j * 8) = z;                              // front 24 rows
    else *(u16x8*)(vbuf + (size_t)8216 * DM + (j - 3072) * 8) = z;          // back 32 rows
  }
}

// GEMM1: vproj[m][n] = sum_k valb[m][k]*Wvb[n][k] + bv[n] -> bf16 rows +VPADF.
// Epilogue: LDS transpose (stride 132 u16, conflict-free) -> coalesced u16x8 stores.
__global__ __launch_bounds__(256) void gemm1_k(const u16* __restrict__ valb,
                                               const u16* __restrict__ Wvb,
                                               const float* __restrict__ bv,
                                               u16* __restrict__ vbuf) {
  __shared__ __align__(16) u16 smem[16896];   // 33 KB: staging 32 KB / epilogue 128x132
  u16* As = smem;
  u16* Bs = smem + 8192;
  int m0, n0; tile_of(blockIdx.x, m0, n0);
  int t = threadIdx.x, lane = t & 63, wave = t >> 6;
  int wm = (wave >> 1) * 64, wn = (wave & 1) * 64;
  int rowin = lane & 7, kc = (lane >> 3) * 8;
  int ldso = lane * 8;
  int lr = lane & 15, kq0 = lane >> 4;
  f32x4 z = {0.f, 0.f, 0.f, 0.f};
  f32x4 acc[4][4];
#pragma unroll
  for (int i = 0; i < 4; i++)
#pragma unroll
    for (int j = 0; j < 4; j++) acc[i][j] = z;

  const u16* Ab = valb + (size_t)m0 * DM;
  const u16* Bb = Wvb + (size_t)n0 * DM;
  for (int k0 = 0; k0 < DM; k0 += 64) {
    STAGE64(Ab + k0, As)
    STAGE64(Bb + k0, Bs)
    __syncthreads();
    MFMA64(As, Bs)
    __syncthreads();
  }

  // scatter acc -> LDS (bf16, padded stride 132), then coalesced global stores
  int q = lane >> 4, col = lane & 15;
#pragma unroll
  for (int j = 0; j < 4; j++) {
    int nl = wn + j * 16 + col;
    float bvn = bv[n0 + nl];
#pragma unroll
    for (int i = 0; i < 4; i++) {
      int ml = wm + i * 16 + q * 4;
#pragma unroll
      for (int r = 0; r < 4; r++)
        smem[(ml + r) * 132 + nl] = f2bf(acc[i][j][r] + bvn);
    }
  }
  __syncthreads();
  int cc = (t & 15) * 8;
  int rbase = (t >> 4) * 8;
#pragma unroll
  for (int s = 0; s < 8; s++) {
    int row = rbase + s;
    u16x8 v = *(const u16x8*)(smem + row * 132 + cc);
    *(u16x8*)(vbuf + (size_t)(m0 + row + VPADF) * DM + n0 + cc) = v;
  }
}

// GEMM2: x[m][n] = sum_k gather(vproj)[m][k]*Wob[n][k] + bo[n] + query[m][n]
// gather = per-head row shift (h-3)*8, absorbed into A base via vbuf pad rows.
// k0 steps of 64 stay within one head (head width 128).
__global__ __launch_bounds__(256) void gemm2_k(const u16* __restrict__ vbuf,
                                               const u16* __restrict__ Wob,
                                               const float* __restrict__ bo,
                                               const float* __restrict__ query,
                                               float* __restrict__ xo) {
  __shared__ __align__(16) u16 smem[16384];   // 32 KB staging
  u16* As = smem;
  u16* Bs = smem + 8192;
  int m0, n0; tile_of(blockIdx.x, m0, n0);
  int t = threadIdx.x, lane = t & 63, wave = t >> 6;
  int wm = (wave >> 1) * 64, wn = (wave & 1) * 64;
  int rowin = lane & 7, kc = (lane >> 3) * 8;
  int ldso = lane * 8;
  int lr = lane & 15, kq0 = lane >> 4;
  f32x4 z = {0.f, 0.f, 0.f, 0.f};
  f32x4 acc[4][4];
#pragma unroll
  for (int i = 0; i < 4; i++)
#pragma unroll
    for (int j = 0; j < 4; j++) acc[i][j] = z;

  const u16* Bb = Wob + (size_t)n0 * DM;
  for (int k0 = 0; k0 < DM; k0 += 64) {
    int h = k0 >> 7;                                   // head for this k-block
    const u16* ab = vbuf + (size_t)(m0 + (h - 3) * 8 + VPADF) * DM + k0;
    STAGE64(ab, As)
    STAGE64(Bb + k0, Bs)
    __syncthreads();
    MFMA64(As, Bs)
    __syncthreads();
  }

  int q = lane >> 4, col = lane & 15;
#pragma unroll
  for (int j = 0; j < 4; j++) {
    int n = n0 + wn + j * 16 + col;
    float bon = bo[n];
#pragma unroll
    for (int i = 0; i < 4; i++) {
      int mb = m0 + wm + i * 16 + q * 4;
#pragma unroll
      for (int r = 0; r < 4; r++) {
        size_t idx = (size_t)(mb + r) * DM + n;
        xo[idx] = acc[i][j][r] + bon + query[idx];
      }
    }
  }
}

// In-place LayerNorm over last dim (1024), one wave per row
__global__ __launch_bounds__(256) void ln_k(float* __restrict__ x,
                                            const float* __restrict__ gamma,
                                            const float* __restrict__ beta) {
  int lane = threadIdx.x & 63, wave = threadIdx.x >> 6;
  size_t row = (size_t)blockIdx.x * 4 + wave;
  float4* p = (float4*)(x + row * DM);
  float4 v[4];
  float s = 0.f, ss = 0.f;
#pragma unroll
  for (int i = 0; i < 4; i++) {
    v[i] = p[i * 64 + lane];
    s  += v[i].x + v[i].y + v[i].z + v[i].w;
    ss += v[i].x * v[i].x + v[i].y * v[i].y + v[i].z * v[i].z + v[i].w * v[i].w;
  }
#pragma unroll
  for (int o = 32; o > 0; o >>= 1) {
    s  += __shfl_xor(s, o);
    ss += __shfl_xor(ss, o);
  }
  float mu = s * (1.0f / 1024.0f);
  float var = ss * (1.0f / 1024.0f) - mu * mu;
  float rstd = rsqrtf(var + 1e-5f);
  const float4* g4 = (const float4*)gamma;
  const float4* b4 = (const float4*)beta;
#pragma unroll
  for (int i = 0; i < 4; i++) {
    float4 g = g4[i * 64 + lane], bb = b4[i * 64 + lane];
    float4 o;
    o.x = (v[i].x - mu) * rstd * g.x + bb.x;
    o.y = (v[i].y - mu) * rstd * g.y + bb.y;
    o.z = (v[i].z - mu) * rstd * g.z + bb.z;
    o.w = (v[i].w - mu) * rstd * g.w + bb.w;
    p[i * 64 + lane] = o;
  }
}

// Fused attn writer: zeros + one-hot in a single aligned float4 stream.
// attn flat layout: [hb(64)][l(1024)][t(1025)], 16793600 float4 total.
// hot(row=hb*1024+l): h=row>>13, l=row&1023, j=l+h-3; hot = (0<=j<=1024)?j:1024.
__global__ __launch_bounds__(256) void fillones_k(float4* __restrict__ p, int n4) {
  int i = blockIdx.x * 256 + threadIdx.x;
  int stride = gridDim.x * 256;
  for (; i < n4; i += stride) {
    unsigned x = (unsigned)i << 2;                       // linear float index
    unsigned row0 = (unsigned)(((unsigned long long)x * 4290777085ULL) >> 42);
    int t0 = (int)(x - row0 * 1025u);
    float4 v;
#pragma unroll
    for (int c = 0; c < 4; c++) {
      int tc = t0 + c;
      unsigned rc = row0 + (tc >= 1025);
      tc -= (tc >= 1025) ? 1025 : 0;
      int h = rc >> 13;
      int l = rc & 1023;
      int j = l + h - 3;
      int hot = ((unsigned)j <= 1024u) ? j : 1024;
      ((float*)&v)[c] = (tc == hot) ? 1.0f : 0.0f;
    }
    p[i] = v;
  }
}

extern "C" void kernel_launch(void* const* d_in, const int* in_sizes, int n_in,
                              void* d_out, int out_size, void* d_ws, size_t ws_size,
                              hipStream_t stream) {
  const float* query = (const float*)d_in[0];
  // d_in[1] key, d_in[3..6] Wq/bq/Wk/bk: dead code (scores overwritten by bias)
  const float* value = (const float*)d_in[2];
  const float* Wv    = (const float*)d_in[7];
  const float* bv    = (const float*)d_in[8];
  const float* Wo    = (const float*)d_in[9];
  const float* bo    = (const float*)d_in[10];
  const float* gamma = (const float*)d_in[11];
  const float* beta  = (const float*)d_in[12];

  float* out  = (float*)d_out;
  float* attn = out + OUTOFF;
  // Scratch lives inside the attn region (268.7 MB); fillones_k runs after
  // gemm2 consumed it (in-order stream). Layout, 16B aligned:
  char* scr = (char*)attn;
  u16* vbuf = (u16*)scr;                              // 8248*1024*2 = 16,891,904 B
  u16* valb = (u16*)(scr + 16891904);                 // 16,777,216 B
  u16* Wvb  = (u16*)(scr + 33669120);                 //  2,097,152 B
  u16* Wob  = (u16*)(scr + 35766272);                 //  2,097,152 B

  dim3 blk(256);
  convert_k<<<5148, blk, 0, stream>>>(value, Wv, Wo, valb, Wvb, Wob, vbuf);
  gemm1_k<<<512, blk, 0, stream>>>(valb, Wvb, bv, vbuf);
  gemm2_k<<<512, blk, 0, stream>>>(vbuf, Wob, bo, query, out);
  ln_k<<<2048, blk, 0, stream>>>(out, gamma, beta);
  fillones_k<<<8192, blk, 0, stream>>>((float4*)attn, 16793600);
}

// Round 5
// 459.283 us; speedup vs baseline: 1.0419x; 1.0419x over previous
//
#include <hip/hip_runtime.h>

// Problem constants
#define DM   1024
#define MR   8192          // L*B rows
#define LKK  1025
#define OUTOFF 8388608     // MR*DM floats, start of attn region in d_out
#define VPADF 24           // front pad rows of vbuf (covers shift -3..-1)

typedef short bf16x8 __attribute__((ext_vector_type(8)));
typedef float f32x4  __attribute__((ext_vector_type(4)));
typedef unsigned short u16;
typedef u16 u16x8 __attribute__((ext_vector_type(8)));

__device__ __forceinline__ u16 f2bf(float f) {
  union { float f; unsigned u; } v; v.f = f;
  return (u16)((v.u + 0x7fffu + ((v.u >> 16) & 1u)) >> 16);  // RNE
}

__device__ __forceinline__ void gl_lds16(const u16* g, u16* l) {
  __builtin_amdgcn_global_load_lds((const __attribute__((address_space(1))) void*)g,
                                   (__attribute__((address_space(3))) void*)l,
                                   16, 0, 0);
}

// Stage a 128x32 bf16 tile (row stride DM) into unpadded LDS [128][32].
// Lane i of wave w, round r: global row r*64+w*16+(i>>2), k-chunk (i&3)*8;
// LDS dest = wave-uniform base + lane*16B (global_load_lds constraint).
// (m97-verified structure: 874 TF at 4096^3 — keep exactly.)
__device__ __forceinline__ void stage_lds(const u16* gbase, u16* lds,
                                          int wave, int sub, int ko) {
#pragma unroll
  for (int r = 0; r < 2; r++) {
    gl_lds16(gbase + (size_t)(r * 64 + wave * 16 + sub) * DM + ko,
             lds + r * 2048 + wave * 512);
  }
}

// One BK=32 MFMA block: each wave computes 64x64 via 4x4 frags of 16x16x32
__device__ __forceinline__ void mfma_step(const u16* As, const u16* Bs,
                                          f32x4 acc[4][4],
                                          int wm, int wn, int lr, int q8) {
  bf16x8 af[4], bf[4];
#pragma unroll
  for (int i = 0; i < 4; i++)
    af[i] = *(const bf16x8*)(As + (wm + i * 16 + lr) * 32 + q8);
#pragma unroll
  for (int j = 0; j < 4; j++)
    bf[j] = *(const bf16x8*)(Bs + (wn + j * 16 + lr) * 32 + q8);
#pragma unroll
  for (int i = 0; i < 4; i++)
#pragma unroll
    for (int j = 0; j < 4; j++)
      acc[i][j] = __builtin_amdgcn_mfma_f32_16x16x32_bf16(af[i], bf[j], acc[i][j], 0, 0, 0);
}

// XCD-friendly tile mapping for 512 blocks (64 m-tiles x 8 n-tiles):
// XCD = blockIdx % 8 sees only 8 m-tiles -> A slice 2MB + B 2MB fit per-XCD L2.
__device__ __forceinline__ void tile_of(int b, int& m0, int& n0) {
  int mt = (b & 7) * 8 + ((b >> 3) & 7);
  int nt = b >> 6;
  m0 = mt * 128; n0 = nt * 128;
}

// Convert value/Wv/Wo f32->bf16 and zero vbuf pad rows. 8 elems/thread.
__global__ __launch_bounds__(256) void convert_k(const float* __restrict__ value,
                                                 const float* __restrict__ Wv,
                                                 const float* __restrict__ Wo,
                                                 u16* __restrict__ valb,
                                                 u16* __restrict__ Wvb,
                                                 u16* __restrict__ Wob,
                                                 u16* __restrict__ vbuf) {
  size_t c = (size_t)blockIdx.x * 256 + threadIdx.x;
  const size_t C1 = 1048576;            // value: 8388608/8
  const size_t C2 = C1 + 131072;        // + Wv
  const size_t C3 = C2 + 131072;        // + Wo = 1310720
  const size_t C4 = C3 + 7168;          // + pad rows (24+32 rows)
  if (c < C3) {
    const float* s; u16* d; size_t off;
    if (c < C1)      { s = value; d = valb; off = c * 8; }
    else if (c < C2) { s = Wv;    d = Wvb;  off = (c - C1) * 8; }
    else             { s = Wo;    d = Wob;  off = (c - C2) * 8; }
    float4 a = *(const float4*)(s + off);
    float4 b = *(const float4*)(s + off + 4);
    u16x8 p;
    p[0]=f2bf(a.x); p[1]=f2bf(a.y); p[2]=f2bf(a.z); p[3]=f2bf(a.w);
    p[4]=f2bf(b.x); p[5]=f2bf(b.y); p[6]=f2bf(b.z); p[7]=f2bf(b.w);
    *(u16x8*)(d + off) = p;
  } else if (c < C4) {
    size_t j = c - C3;
    u16x8 z = {0,0,0,0,0,0,0,0};
    if (j < 3072) *(u16x8*)(vbuf + j * 8) = z;                              // front 24 rows
    else *(u16x8*)(vbuf + (size_t)8216 * DM + (j - 3072) * 8) = z;          // back 32 rows
  }
}

// GEMM1: vproj[m][n] = sum_k valb[m][k]*Wvb[n][k] + bv[n] -> bf16 rows +VPADF.
// Epilogue: LDS transpose (stride 132 u16, conflict-free) -> coalesced u16x8 stores.
__global__ __launch_bounds__(256) void gemm1_k(const u16* __restrict__ valb,
                                               const u16* __restrict__ Wvb,
                                               const float* __restrict__ bv,
                                               u16* __restrict__ vbuf) {
  __shared__ __align__(16) u16 smem[128 * 132];   // 33.8 KB; staging uses first 16 KB
  u16* As = smem;
  u16* Bs = smem + 4096;
  int m0, n0; tile_of(blockIdx.x, m0, n0);
  int t = threadIdx.x, lane = t & 63, wave = t >> 6;
  int wm = (wave >> 1) * 64, wn = (wave & 1) * 64;
  int sub = lane >> 2, ko = (lane & 3) * 8;
  int lr = lane & 15, q8 = (lane >> 4) * 8;
  f32x4 z = {0.f, 0.f, 0.f, 0.f};
  f32x4 acc[4][4];
#pragma unroll
  for (int i = 0; i < 4; i++)
#pragma unroll
    for (int j = 0; j < 4; j++) acc[i][j] = z;

  const u16* Ab = valb + (size_t)m0 * DM;
  const u16* Bb = Wvb + (size_t)n0 * DM;
  for (int k0 = 0; k0 < DM; k0 += 32) {
    stage_lds(Ab + k0, As, wave, sub, ko);
    stage_lds(Bb + k0, Bs, wave, sub, ko);
    __syncthreads();
    mfma_step(As, Bs, acc, wm, wn, lr, q8);
    __syncthreads();
  }

  // scatter acc -> LDS (bf16, padded stride), then coalesced global stores
  int q = lane >> 4, col = lane & 15;
#pragma unroll
  for (int j = 0; j < 4; j++) {
    int nl = wn + j * 16 + col;
    float bvn = bv[n0 + nl];
#pragma unroll
    for (int i = 0; i < 4; i++) {
      int ml = wm + i * 16 + q * 4;
#pragma unroll
      for (int r = 0; r < 4; r++)
        smem[(ml + r) * 132 + nl] = f2bf(acc[i][j][r] + bvn);
    }
  }
  __syncthreads();
  int cc = (t & 15) * 8;
  int rbase = (t >> 4) * 8;
#pragma unroll
  for (int s = 0; s < 8; s++) {
    int row = rbase + s;
    u16x8 v = *(const u16x8*)(smem + row * 132 + cc);
    *(u16x8*)(vbuf + (size_t)(m0 + row + VPADF) * DM + n0 + cc) = v;
  }
}

// GEMM2: x[m][n] = sum_k gather(vproj)[m][k]*Wob[n][k] + bo[n] + query[m][n]
// gather = per-head row shift (h-3)*8, absorbed into A base via vbuf pad rows.
__global__ __launch_bounds__(256) void gemm2_k(const u16* __restrict__ vbuf,
                                               const u16* __restrict__ Wob,
                                               const float* __restrict__ bo,
                                               const float* __restrict__ query,
                                               float* __restrict__ xo) {
  __shared__ __align__(16) u16 As[128 * 32];
  __shared__ __align__(16) u16 Bs[128 * 32];
  int m0, n0; tile_of(blockIdx.x, m0, n0);
  int t = threadIdx.x, lane = t & 63, wave = t >> 6;
  int wm = (wave >> 1) * 64, wn = (wave & 1) * 64;
  int sub = lane >> 2, ko = (lane & 3) * 8;
  int lr = lane & 15, q8 = (lane >> 4) * 8;
  f32x4 z = {0.f, 0.f, 0.f, 0.f};
  f32x4 acc[4][4];
#pragma unroll
  for (int i = 0; i < 4; i++)
#pragma unroll
    for (int j = 0; j < 4; j++) acc[i][j] = z;

  const u16* Bb = Wob + (size_t)n0 * DM;
  for (int k0 = 0; k0 < DM; k0 += 32) {
    int h = k0 >> 7;                                   // head for this k-block
    const u16* ab = vbuf + (size_t)(m0 + (h - 3) * 8 + VPADF) * DM + k0;
    stage_lds(ab, As, wave, sub, ko);
    stage_lds(Bb + k0, Bs, wave, sub, ko);
    __syncthreads();
    mfma_step(As, Bs, acc, wm, wn, lr, q8);
    __syncthreads();
  }

  int q = lane >> 4, col = lane & 15;
#pragma unroll
  for (int j = 0; j < 4; j++) {
    int n = n0 + wn + j * 16 + col;
    float bon = bo[n];
#pragma unroll
    for (int i = 0; i < 4; i++) {
      int mb = m0 + wm + i * 16 + q * 4;
#pragma unroll
      for (int r = 0; r < 4; r++) {
        size_t idx = (size_t)(mb + r) * DM + n;
        xo[idx] = acc[i][j][r] + bon + query[idx];
      }
    }
  }
}

// Fused LayerNorm + attn one-hot writer.
// Blocks 0..2047: in-place LN over rows of x (one wave per row).
// Blocks 2048..10239: grid-stride float4 fill of attn (zeros + one-hot).
__global__ __launch_bounds__(256) void lnfill_k(float* __restrict__ x,
                                                const float* __restrict__ gamma,
                                                const float* __restrict__ beta,
                                                float4* __restrict__ attn4, int n4) {
  int blk = blockIdx.x;
  if (blk < 2048) {
    int lane = threadIdx.x & 63, wave = threadIdx.x >> 6;
    size_t row = (size_t)blk * 4 + wave;
    float4* p = (float4*)(x + row * DM);
    float4 v[4];
    float s = 0.f, ss = 0.f;
#pragma unroll
    for (int i = 0; i < 4; i++) {
      v[i] = p[i * 64 + lane];
      s  += v[i].x + v[i].y + v[i].z + v[i].w;
      ss += v[i].x * v[i].x + v[i].y * v[i].y + v[i].z * v[i].z + v[i].w * v[i].w;
    }
#pragma unroll
    for (int o = 32; o > 0; o >>= 1) {
      s  += __shfl_xor(s, o);
      ss += __shfl_xor(ss, o);
    }
    float mu = s * (1.0f / 1024.0f);
    float var = ss * (1.0f / 1024.0f) - mu * mu;
    float rstd = rsqrtf(var + 1e-5f);
    const float4* g4 = (const float4*)gamma;
    const float4* b4 = (const float4*)beta;
#pragma unroll
    for (int i = 0; i < 4; i++) {
      float4 g = g4[i * 64 + lane], bb = b4[i * 64 + lane];
      float4 o;
      o.x = (v[i].x - mu) * rstd * g.x + bb.x;
      o.y = (v[i].y - mu) * rstd * g.y + bb.y;
      o.z = (v[i].z - mu) * rstd * g.z + bb.z;
      o.w = (v[i].w - mu) * rstd * g.w + bb.w;
      p[i * 64 + lane] = o;
    }
  } else {
    // attn flat layout: [hb(64)][l(1024)][t(1025)], 16793600 float4 total.
    // hot(row=hb*1024+l): h=row>>13, l=row&1023, j=l+h-3; hot=(0<=j<=1024)?j:1024.
    int i = (blk - 2048) * 256 + threadIdx.x;
    int stride = (gridDim.x - 2048) * 256;
    for (; i < n4; i += stride) {
      unsigned xf = (unsigned)i << 2;                     // linear float index
      unsigned row0 = (unsigned)(((unsigned long long)xf * 4290777085ULL) >> 42);
      int t0 = (int)(xf - row0 * 1025u);
      float4 v;
#pragma unroll
      for (int c = 0; c < 4; c++) {
        int tc = t0 + c;
        unsigned rc = row0 + (tc >= 1025);
        tc -= (tc >= 1025) ? 1025 : 0;
        int h = rc >> 13;
        int l = rc & 1023;
        int j = l + h - 3;
        int hot = ((unsigned)j <= 1024u) ? j : 1024;
        ((float*)&v)[c] = (tc == hot) ? 1.0f : 0.0f;
      }
      attn4[i] = v;
    }
  }
}

extern "C" void kernel_launch(void* const* d_in, const int* in_sizes, int n_in,
                              void* d_out, int out_size, void* d_ws, size_t ws_size,
                              hipStream_t stream) {
  const float* query = (const float*)d_in[0];
  // d_in[1] key, d_in[3..6] Wq/bq/Wk/bk: dead code (scores overwritten by bias)
  const float* value = (const float*)d_in[2];
  const float* Wv    = (const float*)d_in[7];
  const float* bv    = (const float*)d_in[8];
  const float* Wo    = (const float*)d_in[9];
  const float* bo    = (const float*)d_in[10];
  const float* gamma = (const float*)d_in[11];
  const float* beta  = (const float*)d_in[12];

  float* out  = (float*)d_out;
  float* attn = out + OUTOFF;
  // Scratch lives inside the attn region (268.7 MB); the fill half of lnfill_k
  // runs after gemm2 consumed it (in-order stream). Layout, 16B aligned:
  char* scr = (char*)attn;
  u16* vbuf = (u16*)scr;                              // 8248*1024*2 = 16,891,904 B
  u16* valb = (u16*)(scr + 16891904);                 // 16,777,216 B
  u16* Wvb  = (u16*)(scr + 33669120);                 //  2,097,152 B
  u16* Wob  = (u16*)(scr + 35766272);                 //  2,097,152 B

  dim3 blk(256);
  convert_k<<<5148, blk, 0, stream>>>(value, Wv, Wo, valb, Wvb, Wob, vbuf);
  gemm1_k<<<512, blk, 0, stream>>>(valb, Wvb, bv, vbuf);
  gemm2_k<<<512, blk, 0, stream>>>(vbuf, Wob, bo, query, out);
  lnfill_k<<<10240, blk, 0, stream>>>(out, gamma, beta, (float4*)attn, 16793600);
}

// Round 6
// 456.959 us; speedup vs baseline: 1.0472x; 1.0051x over previous
//
#include <hip/hip_runtime.h>

// Problem constants
#define DM   1024
#define MR   8192          // L*B rows
#define LKK  1025
#define OUTOFF 8388608     // MR*DM floats, start of attn region in d_out
#define VPADF 24           // front pad rows of vbuf (covers shift -3..-1)

typedef short bf16x8 __attribute__((ext_vector_type(8)));
typedef float f32x4  __attribute__((ext_vector_type(4)));
typedef unsigned short u16;
typedef u16 u16x8 __attribute__((ext_vector_type(8)));

__device__ __forceinline__ u16 f2bf(float f) {
  union { float f; unsigned u; } v; v.f = f;
  return (u16)((v.u + 0x7fffu + ((v.u >> 16) & 1u)) >> 16);  // RNE
}

__device__ __forceinline__ void gl_lds16(const u16* g, u16* l) {
  __builtin_amdgcn_global_load_lds((const __attribute__((address_space(1))) void*)g,
                                   (__attribute__((address_space(3))) void*)l,
                                   16, 0, 0);
}

// 512-thread staging: one round stages a full 128x32 bf16 tile.
// Wave w covers rows w*16..w*16+15: lane i -> row w*16+(i>>2), k-chunk (i&3)*8.
// LDS dest = wave-uniform base w*512 + lane*8 u16 (HW: base + lane*16B).
// Resulting layout: addr(row,kq) = (row>>4)*512 + (row&15)*32 + kq*8.
// Frag reads: row-group uniform per frag, 64B row stride (m97-proven pattern).

// XCD-friendly tile mapping for 512 blocks (64 m-tiles x 8 n-tiles):
// XCD = blockIdx % 8 sees only 8 m-tiles -> A slice 2MB + B 2MB fit per-XCD L2.
__device__ __forceinline__ void tile_of(int b, int& m0, int& n0) {
  int mt = (b & 7) * 8 + ((b >> 3) & 7);
  int nt = b >> 6;
  m0 = mt * 128; n0 = nt * 128;
}

// Convert value/Wv/Wo f32->bf16 and zero vbuf pad rows. 8 elems/thread.
__global__ __launch_bounds__(256) void convert_k(const float* __restrict__ value,
                                                 const float* __restrict__ Wv,
                                                 const float* __restrict__ Wo,
                                                 u16* __restrict__ valb,
                                                 u16* __restrict__ Wvb,
                                                 u16* __restrict__ Wob,
                                                 u16* __restrict__ vbuf) {
  size_t c = (size_t)blockIdx.x * 256 + threadIdx.x;
  const size_t C1 = 1048576;            // value: 8388608/8
  const size_t C2 = C1 + 131072;        // + Wv
  const size_t C3 = C2 + 131072;        // + Wo = 1310720
  const size_t C4 = C3 + 7168;          // + pad rows (24+32 rows)
  if (c < C3) {
    const float* s; u16* d; size_t off;
    if (c < C1)      { s = value; d = valb; off = c * 8; }
    else if (c < C2) { s = Wv;    d = Wvb;  off = (c - C1) * 8; }
    else             { s = Wo;    d = Wob;  off = (c - C2) * 8; }
    float4 a = *(const float4*)(s + off);
    float4 b = *(const float4*)(s + off + 4);
    u16x8 p;
    p[0]=f2bf(a.x); p[1]=f2bf(a.y); p[2]=f2bf(a.z); p[3]=f2bf(a.w);
    p[4]=f2bf(b.x); p[5]=f2bf(b.y); p[6]=f2bf(b.z); p[7]=f2bf(b.w);
    *(u16x8*)(d + off) = p;
  } else if (c < C4) {
    size_t j = c - C3;
    u16x8 z = {0,0,0,0,0,0,0,0};
    if (j < 3072) *(u16x8*)(vbuf + j * 8) = z;                              // front 24 rows
    else *(u16x8*)(vbuf + (size_t)8216 * DM + (j - 3072) * 8) = z;          // back 32 rows
  }
}

// GEMM1: vproj[m][n] = sum_k valb[m][k]*Wvb[n][k] + bv[n] -> bf16 rows +VPADF.
// 512 threads/block (8 waves, 2x4 arrangement, 64x32 per wave) -> 16 waves/CU.
// Epilogue: LDS transpose (stride 132, conflict-free) -> coalesced u16x8 stores.
__global__ __launch_bounds__(512, 4) void gemm1_k(const u16* __restrict__ valb,
                                                  const u16* __restrict__ Wvb,
                                                  const float* __restrict__ bv,
                                                  u16* __restrict__ vbuf) {
  __shared__ __align__(16) u16 smem[16896];   // 33 KB: staging 16 KB / epilogue 128x132
  u16* As = smem;
  u16* Bs = smem + 4096;
  int m0, n0; tile_of(blockIdx.x, m0, n0);
  int t = threadIdx.x, lane = t & 63, wave = t >> 6;
  int wm = (wave >> 2) * 64, wn = (wave & 3) * 32;
  int srow = wave * 16 + (lane >> 2);         // staging row 0..127
  int ko = (lane & 3) * 8;                    // staging k offset
  int ldso = wave * 512;                      // staging LDS base (wave-uniform)
  int lr = lane & 15, kq8 = (lane >> 4) * 8;  // frag indices
  f32x4 z = {0.f, 0.f, 0.f, 0.f};
  f32x4 acc[4][2];
#pragma unroll
  for (int i = 0; i < 4; i++)
#pragma unroll
    for (int j = 0; j < 2; j++) acc[i][j] = z;

  const u16* Ab = valb + (size_t)(m0 + srow) * DM + ko;
  const u16* Bb = Wvb + (size_t)(n0 + srow) * DM + ko;
  for (int k0 = 0; k0 < DM; k0 += 32) {
    gl_lds16(Ab + k0, As + ldso);
    gl_lds16(Bb + k0, Bs + ldso);
    __syncthreads();
    bf16x8 af[4], bf[2];
#pragma unroll
    for (int i = 0; i < 4; i++) {
      int row = wm + i * 16;
      af[i] = *(const bf16x8*)(As + (row >> 4) * 512 + lr * 32 + kq8);
    }
#pragma unroll
    for (int j = 0; j < 2; j++) {
      int row = wn + j * 16;
      bf[j] = *(const bf16x8*)(Bs + (row >> 4) * 512 + lr * 32 + kq8);
    }
#pragma unroll
    for (int i = 0; i < 4; i++)
#pragma unroll
      for (int j = 0; j < 2; j++)
        acc[i][j] = __builtin_amdgcn_mfma_f32_16x16x32_bf16(af[i], bf[j], acc[i][j], 0, 0, 0);
    __syncthreads();
  }

  // scatter acc -> LDS (bf16, padded stride 132), then coalesced global stores
  int q = lane >> 4, col = lane & 15;
#pragma unroll
  for (int j = 0; j < 2; j++) {
    int nl = wn + j * 16 + col;
    float bvn = bv[n0 + nl];
#pragma unroll
    for (int i = 0; i < 4; i++) {
      int ml = wm + i * 16 + q * 4;
#pragma unroll
      for (int r = 0; r < 4; r++)
        smem[(ml + r) * 132 + nl] = f2bf(acc[i][j][r] + bvn);
    }
  }
  __syncthreads();
  int cc = (t & 15) * 8;
  int rbase = (t >> 4) * 4;
#pragma unroll
  for (int s = 0; s < 4; s++) {
    int row = rbase + s;
    u16x8 v = *(const u16x8*)(smem + row * 132 + cc);
    *(u16x8*)(vbuf + (size_t)(m0 + row + VPADF) * DM + n0 + cc) = v;
  }
}

// GEMM2: x[m][n] = sum_k gather(vproj)[m][k]*Wob[n][k] + bo[n] + query[m][n]
// gather = per-head row shift (h-3)*8, absorbed into A base via vbuf pad rows.
__global__ __launch_bounds__(512, 4) void gemm2_k(const u16* __restrict__ vbuf,
                                                  const u16* __restrict__ Wob,
                                                  const float* __restrict__ bo,
                                                  const float* __restrict__ query,
                                                  float* __restrict__ xo) {
  __shared__ __align__(16) u16 smem[8192];    // 16 KB staging
  u16* As = smem;
  u16* Bs = smem + 4096;
  int m0, n0; tile_of(blockIdx.x, m0, n0);
  int t = threadIdx.x, lane = t & 63, wave = t >> 6;
  int wm = (wave >> 2) * 64, wn = (wave & 3) * 32;
  int srow = wave * 16 + (lane >> 2);
  int ko = (lane & 3) * 8;
  int ldso = wave * 512;
  int lr = lane & 15, kq8 = (lane >> 4) * 8;
  f32x4 z = {0.f, 0.f, 0.f, 0.f};
  f32x4 acc[4][2];
#pragma unroll
  for (int i = 0; i < 4; i++)
#pragma unroll
    for (int j = 0; j < 2; j++) acc[i][j] = z;

  const u16* Ab = vbuf + (size_t)(m0 + srow + VPADF) * DM + ko;
  const u16* Bb = Wob + (size_t)(n0 + srow) * DM + ko;
  for (int k0 = 0; k0 < DM; k0 += 32) {
    int h = k0 >> 7;                                   // head for this k-block
    gl_lds16(Ab + (size_t)((h - 3) * 8) * DM + k0, As + ldso);
    gl_lds16(Bb + k0, Bs + ldso);
    __syncthreads();
    bf16x8 af[4], bf[2];
#pragma unroll
    for (int i = 0; i < 4; i++) {
      int row = wm + i * 16;
      af[i] = *(const bf16x8*)(As + (row >> 4) * 512 + lr * 32 + kq8);
    }
#pragma unroll
    for (int j = 0; j < 2; j++) {
      int row = wn + j * 16;
      bf[j] = *(const bf16x8*)(Bs + (row >> 4) * 512 + lr * 32 + kq8);
    }
#pragma unroll
    for (int i = 0; i < 4; i++)
#pragma unroll
      for (int j = 0; j < 2; j++)
        acc[i][j] = __builtin_amdgcn_mfma_f32_16x16x32_bf16(af[i], bf[j], acc[i][j], 0, 0, 0);
    __syncthreads();
  }

  int q = lane >> 4, col = lane & 15;
#pragma unroll
  for (int j = 0; j < 2; j++) {
    int n = n0 + wn + j * 16 + col;
    float bon = bo[n];
#pragma unroll
    for (int i = 0; i < 4; i++) {
      int mb = m0 + wm + i * 16 + q * 4;
#pragma unroll
      for (int r = 0; r < 4; r++) {
        size_t idx = (size_t)(mb + r) * DM + n;
        xo[idx] = acc[i][j][r] + bon + query[idx];
      }
    }
  }
}

// Fused LayerNorm + attn one-hot writer.
// Blocks 0..2047: in-place LN over rows of x (one wave per row).
// Blocks 2048..10239: grid-stride float4 fill of attn (zeros + one-hot).
__global__ __launch_bounds__(256) void lnfill_k(float* __restrict__ x,
                                                const float* __restrict__ gamma,
                                                const float* __restrict__ beta,
                                                float4* __restrict__ attn4, int n4) {
  int blk = blockIdx.x;
  if (blk < 2048) {
    int lane = threadIdx.x & 63, wave = threadIdx.x >> 6;
    size_t row = (size_t)blk * 4 + wave;
    float4* p = (float4*)(x + row * DM);
    float4 v[4];
    float s = 0.f, ss = 0.f;
#pragma unroll
    for (int i = 0; i < 4; i++) {
      v[i] = p[i * 64 + lane];
      s  += v[i].x + v[i].y + v[i].z + v[i].w;
      ss += v[i].x * v[i].x + v[i].y * v[i].y + v[i].z * v[i].z + v[i].w * v[i].w;
    }
#pragma unroll
    for (int o = 32; o > 0; o >>= 1) {
      s  += __shfl_xor(s, o);
      ss += __shfl_xor(ss, o);
    }
    float mu = s * (1.0f / 1024.0f);
    float var = ss * (1.0f / 1024.0f) - mu * mu;
    float rstd = rsqrtf(var + 1e-5f);
    const float4* g4 = (const float4*)gamma;
    const float4* b4 = (const float4*)beta;
#pragma unroll
    for (int i = 0; i < 4; i++) {
      float4 g = g4[i * 64 + lane], bb = b4[i * 64 + lane];
      float4 o;
      o.x = (v[i].x - mu) * rstd * g.x + bb.x;
      o.y = (v[i].y - mu) * rstd * g.y + bb.y;
      o.z = (v[i].z - mu) * rstd * g.z + bb.z;
      o.w = (v[i].w - mu) * rstd * g.w + bb.w;
      p[i * 64 + lane] = o;
    }
  } else {
    // attn flat layout: [hb(64)][l(1024)][t(1025)], 16793600 float4 total.
    // hot(row=hb*1024+l): h=row>>13, l=row&1023, j=l+h-3; hot=(0<=j<=1024)?j:1024.
    int i = (blk - 2048) * 256 + threadIdx.x;
    int stride = (gridDim.x - 2048) * 256;
    for (; i < n4; i += stride) {
      unsigned xf = (unsigned)i << 2;                     // linear float index
      unsigned row0 = (unsigned)(((unsigned long long)xf * 4290777085ULL) >> 42);
      int t0 = (int)(xf - row0 * 1025u);
      float4 v;
#pragma unroll
      for (int c = 0; c < 4; c++) {
        int tc = t0 + c;
        unsigned rc = row0 + (tc >= 1025);
        tc -= (tc >= 1025) ? 1025 : 0;
        int h = rc >> 13;
        int l = rc & 1023;
        int j = l + h - 3;
        int hot = ((unsigned)j <= 1024u) ? j : 1024;
        ((float*)&v)[c] = (tc == hot) ? 1.0f : 0.0f;
      }
      attn4[i] = v;
    }
  }
}

extern "C" void kernel_launch(void* const* d_in, const int* in_sizes, int n_in,
                              void* d_out, int out_size, void* d_ws, size_t ws_size,
                              hipStream_t stream) {
  const float* query = (const float*)d_in[0];
  // d_in[1] key, d_in[3..6] Wq/bq/Wk/bk: dead code (scores overwritten by bias)
  const float* value = (const float*)d_in[2];
  const float* Wv    = (const float*)d_in[7];
  const float* bv    = (const float*)d_in[8];
  const float* Wo    = (const float*)d_in[9];
  const float* bo    = (const float*)d_in[10];
  const float* gamma = (const float*)d_in[11];
  const float* beta  = (const float*)d_in[12];

  float* out  = (float*)d_out;
  float* attn = out + OUTOFF;
  // Scratch lives inside the attn region (268.7 MB); the fill half of lnfill_k
  // runs after gemm2 consumed it (in-order stream). Layout, 16B aligned:
  char* scr = (char*)attn;
  u16* vbuf = (u16*)scr;                              // 8248*1024*2 = 16,891,904 B
  u16* valb = (u16*)(scr + 16891904);                 // 16,777,216 B
  u16* Wvb  = (u16*)(scr + 33669120);                 //  2,097,152 B
  u16* Wob  = (u16*)(scr + 35766272);                 //  2,097,152 B

  convert_k<<<5148, 256, 0, stream>>>(value, Wv, Wo, valb, Wvb, Wob, vbuf);
  gemm1_k<<<512, 512, 0, stream>>>(valb, Wvb, bv, vbuf);
  gemm2_k<<<512, 512, 0, stream>>>(vbuf, Wob, bo, query, out);
  lnfill_k<<<10240, 256, 0, stream>>>(out, gamma, beta, (float4*)attn, 16793600);
}